// Round 10
// baseline (278.645 us; speedup 1.0000x reference)
//
#include <hip/hip_runtime.h>
#include <math.h>

#define NNODES 50000
#define NEDGES 800000
#define GB 782            // row-blocks = (NNODES+63)/64

typedef _Float16 f16;
typedef _Float16 f16x8 __attribute__((ext_vector_type(8)));
typedef _Float16 f16x4 __attribute__((ext_vector_type(4)));
typedef _Float16 f16x2 __attribute__((ext_vector_type(2)));
typedef float f32x4 __attribute__((ext_vector_type(4)));
typedef float f32x8 __attribute__((ext_vector_type(8)));
typedef unsigned short u16;

// ---------------- CSR build + weight pack ----------------

__global__ __launch_bounds__(256) void k_deg_wfrag(const int* __restrict__ ei, int* __restrict__ deg,
                                                   int* __restrict__ rank,
                                                   const float* __restrict__ W1, const float* __restrict__ W2,
                                                   f16* __restrict__ W1f, f16* __restrict__ W2f) {
    int bid = blockIdx.x;
    if (bid < NEDGES / 256) {
        int e = bid * 256 + threadIdx.x;
        rank[e] = atomicAdd(&deg[ei[NEDGES + e]], 1);
    } else {
        int id = (bid - NEDGES / 256) * 256 + threadIdx.x;
        if (id < 32768) {  // W1: 128 x 256
            int k = id >> 8, c = id & 255;
            int kc = k >> 5, quad = (k & 31) >> 3, j = k & 7;
            W1f[(((kc << 8) + c) * 4 + quad) * 8 + j] = (f16)W1[id];
        } else {           // W2: 256 x 32
            int i2 = id - 32768;
            int k = i2 >> 5, c = i2 & 31;
            int kc = k >> 5, quad = (k & 31) >> 3, j = k & 7;
            W2f[(((kc << 5) + c) * 4 + quad) * 8 + j] = (f16)W2[i2];
        }
    }
}

__global__ __launch_bounds__(256) void k_scanA(const int* __restrict__ deg, int* __restrict__ incl,
                                               int* __restrict__ partial) {
    int t = threadIdx.x;
    int i = blockIdx.x * 256 + t;
    int v = (i < NNODES) ? deg[i] : 0;
    int lane = t & 63, wid = t >> 6;
    int s = v;
#pragma unroll
    for (int d = 1; d < 64; d <<= 1) { int u = __shfl_up(s, d, 64); if (lane >= d) s += u; }
    __shared__ int wtot[4];
    if (lane == 63) wtot[wid] = s;
    __syncthreads();
    int off = 0;
    for (int w = 0; w < wid; ++w) off += wtot[w];
    s += off;
    if (i < NNODES) incl[i] = s;
    if (t == 255) partial[blockIdx.x] = s;
}

__global__ __launch_bounds__(256) void k_scanC(const int* __restrict__ deg, const int* __restrict__ incl,
                                               const int* __restrict__ partial, int* __restrict__ rowst) {
    int t = threadIdx.x, bid = blockIdx.x;
    int v = (t < bid) ? partial[t] : 0;  // bid <= 195 < 256
    int lane = t & 63, wid = t >> 6;
#pragma unroll
    for (int d = 1; d < 64; d <<= 1) v += __shfl_xor(v, d);
    __shared__ int ws[4];
    if (lane == 0) ws[wid] = v;
    __syncthreads();
    int choff = ws[0] + ws[1] + ws[2] + ws[3];
    int i = bid * 256 + t;
    if (i < NNODES) {
        int rs1 = incl[i] + choff;
        rowst[i + 1] = rs1;
        if (i == 0) rowst[0] = 0;
    }
}

// ---------------- gemm1 + atomic-free thin scatter (merged grid) ----------------
// Wave-per-64-col strip (R3); head-major h1s[head][node][32] (R4);
// node-major f32 alphas as1n/ad1n[N][8] for k_exp's 32B endpoint gathers (R7).

__global__ __launch_bounds__(256) void k_gemm1_sc(const float* __restrict__ X, const f16* __restrict__ W1f,
                                                  const float* __restrict__ Asrc, const float* __restrict__ Adst,
                                                  f16* __restrict__ h1s, float* __restrict__ as1n,
                                                  float* __restrict__ ad1n, const int* __restrict__ ei,
                                                  const int* __restrict__ rowst, const int* __restrict__ rank,
                                                  unsigned* __restrict__ sd32) {
    __shared__ f16 sA[64 * 136];
    int bid = blockIdx.x;
    int t = threadIdx.x;
    if (bid >= GB) {  // CSR scatter path (uniform per block)
        int e = (bid - GB) * 256 + t;
        if (e < NEDGES) {
            int s = ei[e], d = ei[NEDGES + e];
            int pos = rowst[d] + rank[e];
            sd32[pos] = ((unsigned)d << 16) | (unsigned)s;
        }
        return;
    }
    int bm = bid * 64;
    int lane = t & 63, w = t >> 6;
    int r = lane & 15, quad = lane >> 4;
    int cw = w * 64;  // this wave's column strip = heads {2w, 2w+1}
    f16x8 bf[4][4];
#pragma unroll
    for (int kc = 0; kc < 4; ++kc)
#pragma unroll
        for (int nt = 0; nt < 4; ++nt)
            bf[kc][nt] = *(const f16x8*)&W1f[(((kc << 8) + cw + nt * 16 + r) * 4 + quad) * 8];
#pragma unroll
    for (int i = 0; i < 8; ++i) {
        int idx = i * 256 + t;
        int row = idx >> 5, c4 = (idx & 31) << 2;
        int gr = bm + row;
        float4 v = make_float4(0.f, 0.f, 0.f, 0.f);
        if (gr < NNODES) v = *(const float4*)(X + (size_t)gr * 128 + c4);
        f16x4 h = {(f16)v.x, (f16)v.y, (f16)v.z, (f16)v.w};
        *(f16x4*)&sA[row * 136 + c4] = h;
    }
    __syncthreads();
    f32x4 acc[4][4];
#pragma unroll
    for (int rg = 0; rg < 4; ++rg)
#pragma unroll
        for (int nt = 0; nt < 4; ++nt) acc[rg][nt] = (f32x4){0.f, 0.f, 0.f, 0.f};
#pragma unroll
    for (int kc = 0; kc < 4; ++kc)
#pragma unroll
        for (int rg = 0; rg < 4; ++rg) {
            f16x8 a = *(f16x8*)&sA[(rg * 16 + r) * 136 + kc * 32 + quad * 8];
#pragma unroll
            for (int nt = 0; nt < 4; ++nt)
                acc[rg][nt] = __builtin_amdgcn_mfma_f32_16x16x32_f16(a, bf[kc][nt], acc[rg][nt], 0, 0, 0);
        }
#pragma unroll
    for (int rg = 0; rg < 4; ++rg)
#pragma unroll
        for (int nt = 0; nt < 4; ++nt)
#pragma unroll
            for (int i = 0; i < 4; ++i) {
                int gr = bm + rg * 16 + quad * 4 + i;
                if (gr < NNODES)
                    h1s[((size_t)(2 * w + (nt >> 1)) * NNODES + gr) * 32 + (nt & 1) * 16 + r] =
                        (f16)acc[rg][nt][i];
            }
    float asv[4], adv[4];
#pragma unroll
    for (int nt = 0; nt < 4; ++nt) {
        asv[nt] = Asrc[cw + nt * 16 + r];
        adv[nt] = Adst[cw + nt * 16 + r];
    }
#pragma unroll
    for (int rg = 0; rg < 4; ++rg)
#pragma unroll
        for (int i = 0; i < 4; ++i) {
            int gr = bm + rg * 16 + quad * 4 + i;
#pragma unroll
            for (int hh = 0; hh < 2; ++hh) {
                float ps = acc[rg][2 * hh][i] * asv[2 * hh] + acc[rg][2 * hh + 1][i] * asv[2 * hh + 1];
                float pd = acc[rg][2 * hh][i] * adv[2 * hh] + acc[rg][2 * hh + 1][i] * adv[2 * hh + 1];
#pragma unroll
                for (int off = 1; off < 16; off <<= 1) {
                    ps += __shfl_xor(ps, off);
                    pd += __shfl_xor(pd, off);
                }
                if (r == 0 && gr < NNODES) {
                    as1n[(size_t)gr * 8 + 2 * w + hh] = ps;   // node-major
                    ad1n[(size_t)gr * 8 + 2 * w + hh] = pd;
                }
            }
        }
}

// ---------------- edge-exp precompute ----------------
// Thread-per-edge. One 32B alpha gather per endpoint; leaky+exp for all 8
// heads; writes f16 exp planes eh16[8][E] (12.8 MB total, half of R9's f32 —
// less L2 pressure in agg1) + u16 src index array (agg1/agg2 read 2B).
__global__ __launch_bounds__(256) void k_exp(const unsigned* __restrict__ sd32, const float* __restrict__ as1n,
                                             const float* __restrict__ ad1n, f16* __restrict__ eh16,
                                             u16* __restrict__ sd16) {
    int j = blockIdx.x * 256 + threadIdx.x;
    if (j >= NEDGES) return;
    unsigned q = sd32[j];
    int d = (int)(q >> 16);
    int s = (int)(q & 0xffffu);
    sd16[j] = (u16)s;
    float4 a0 = *(const float4*)(as1n + (size_t)s * 8);
    float4 a1 = *(const float4*)(as1n + (size_t)s * 8 + 4);
    float4 d0 = *(const float4*)(ad1n + (size_t)d * 8);
    float4 d1 = *(const float4*)(ad1n + (size_t)d * 8 + 4);
    float av[8] = {a0.x, a0.y, a0.z, a0.w, a1.x, a1.y, a1.z, a1.w};
    float dv[8] = {d0.x, d0.y, d0.z, d0.w, d1.x, d1.y, d1.z, d1.w};
#pragma unroll
    for (int h = 0; h < 8; ++h) {
        float x = av[h] + dv[h];
        x = fmaxf(x, 0.2f * x);
        eh16[(size_t)h * NEDGES + j] = (f16)__expf(x);
    }
}

// gh[N,32](f16) = h2 @ W2; h2 is head-major h2s[head][node][32] (kc == head).
__global__ __launch_bounds__(256) void k_gemm2(const f16* __restrict__ h2s, const f16* __restrict__ W2f,
                                               const float* __restrict__ Asrc, const float* __restrict__ Adst,
                                               f16* __restrict__ gh, float* __restrict__ as2,
                                               float* __restrict__ ad2) {
    int t = threadIdx.x;
    int bm = blockIdx.x * 64;
    int lane = t & 63, w = t >> 6;
    int r = lane & 15, quad = lane >> 4;
    int r0 = w * 16;
    int gra = bm + r0 + r;
    int grac = gra < NNODES ? gra : 0;
    f32x4 acc[2];
    acc[0] = (f32x4){0.f, 0.f, 0.f, 0.f};
    acc[1] = (f32x4){0.f, 0.f, 0.f, 0.f};
#pragma unroll
    for (int kc = 0; kc < 8; ++kc) {
        f16x8 a = *(const f16x8*)(h2s + ((size_t)kc * NNODES + grac) * 32 + quad * 8);
#pragma unroll
        for (int nt = 0; nt < 2; ++nt) {
            f16x8 b = *(const f16x8*)&W2f[(((kc << 5) + nt * 16 + r) * 4 + quad) * 8];
            acc[nt] = __builtin_amdgcn_mfma_f32_16x16x32_f16(a, b, acc[nt], 0, 0, 0);
        }
    }
#pragma unroll
    for (int nt = 0; nt < 2; ++nt)
#pragma unroll
        for (int i = 0; i < 4; ++i) {
            int gr = bm + r0 + quad * 4 + i;
            if (gr < NNODES) gh[(size_t)gr * 32 + nt * 16 + r] = (f16)acc[nt][i];
        }
    float as0 = Asrc[r], as16 = Asrc[16 + r];
    float ad0 = Adst[r], ad16 = Adst[16 + r];
#pragma unroll
    for (int i = 0; i < 4; ++i) {
        int gr = bm + r0 + quad * 4 + i;
        float ps = acc[0][i] * as0 + acc[1][i] * as16;
        float pd = acc[0][i] * ad0 + acc[1][i] * ad16;
#pragma unroll
        for (int off = 1; off < 16; off <<= 1) {
            ps += __shfl_xor(ps, off);
            pd += __shfl_xor(pd, off);
        }
        if (r == 0 && gr < NNODES) { as2[gr] = ps; ad2[gr] = pd; }
    }
}

// ---------------- fused softmax + aggregate ----------------
// R10: stream-eviction control. R9 post-mortem: exp precompute removed the
// 6.4M alpha-gather lines BUT its f32 streams thrashed the h1s slice out of
// L2 (FETCH 132 MB = 3x compulsory h1s re-fetch; R6's no-stream variant had
// FETCH 30.8 = pure compulsory). Fix: (a) stream reads (sd16/eh16) are
// NONTEMPORAL (nt = evict-first in L2, not bypass) so they pass through
// without displacing the slice; (b) streams halved: f16 exp planes + u16
// indices (3.2 MB/slice). h1s gathers stay normally-cached + slice-resident.
// Wave shape: 16 groups x 4 lanes; group owns one node; no cross-lane reduce;
// forced-live channel-major math (R6).
__global__ __launch_bounds__(256) void k_agg1(const int* __restrict__ rowst, const u16* __restrict__ sd16,
                                              const f16* __restrict__ eh16, const f16* __restrict__ h1s,
                                              const float* __restrict__ b1, f16* __restrict__ h2s) {
    int bid = blockIdx.x;
    int sl = bid & 7;
    int ng = bid >> 3;
    int t = threadIdx.x;
    int w = t >> 6, lane = t & 63;
    int g = lane >> 2, cs = lane & 3;
    int c0 = cs << 3;
    int n = ng * 64 + w * 16 + g;
    if (n >= NNODES) return;
    int s = rowst[n], e = rowst[n + 1];
    const f16* __restrict__ hp = h1s + (size_t)sl * NNODES * 32 + c0;
    const f16* __restrict__ ep = eh16 + (size_t)sl * NEDGES;
    f32x8 acc = (f32x8){0.f, 0.f, 0.f, 0.f, 0.f, 0.f, 0.f, 0.f};
    float sum = 0.f;
    int j = s;
    for (; j + 7 < e; j += 8) {
        int si[8];
#pragma unroll
        for (int u = 0; u < 8; ++u) si[u] = (int)__builtin_nontemporal_load(sd16 + j + u);
        float ee[8];
#pragma unroll
        for (int u = 0; u < 8; ++u) ee[u] = (float)__builtin_nontemporal_load(ep + j + u);
        f16x8 vv[8];
#pragma unroll
        for (int u = 0; u < 8; ++u) vv[u] = *(const f16x8*)(hp + (size_t)si[u] * 32);
#pragma unroll
        for (int u = 0; u < 8; ++u) sum += ee[u];
        // channel-major: all 8 gathers live across the math block (forced MLP)
#pragma unroll
        for (int k = 0; k < 8; ++k) {
            float a = acc[k];
#pragma unroll
            for (int u = 0; u < 8; ++u) a += ee[u] * (float)vv[u][k];
            acc[k] = a;
        }
    }
    for (; j + 3 < e; j += 4) {
        int si[4];
#pragma unroll
        for (int u = 0; u < 4; ++u) si[u] = (int)__builtin_nontemporal_load(sd16 + j + u);
        float ee[4];
#pragma unroll
        for (int u = 0; u < 4; ++u) ee[u] = (float)__builtin_nontemporal_load(ep + j + u);
        f16x8 vv[4];
#pragma unroll
        for (int u = 0; u < 4; ++u) vv[u] = *(const f16x8*)(hp + (size_t)si[u] * 32);
#pragma unroll
        for (int u = 0; u < 4; ++u) sum += ee[u];
#pragma unroll
        for (int k = 0; k < 8; ++k) {
            float a = acc[k];
#pragma unroll
            for (int u = 0; u < 4; ++u) a += ee[u] * (float)vv[u][k];
            acc[k] = a;
        }
    }
    for (; j < e; ++j) {
        int s0 = (int)__builtin_nontemporal_load(sd16 + j);
        float e0 = (float)__builtin_nontemporal_load(ep + j);
        f16x8 v0 = *(const f16x8*)(hp + (size_t)s0 * 32);
        sum += e0;
#pragma unroll
        for (int k = 0; k < 8; ++k) acc[k] += e0 * (float)v0[k];
    }
    float inv = 1.f / (sum + 1e-16f);
    float4 b0 = *(const float4*)(b1 + sl * 32 + c0);
    float4 b4 = *(const float4*)(b1 + sl * 32 + c0 + 4);
    float o[8] = {acc[0] * inv + b0.x, acc[1] * inv + b0.y, acc[2] * inv + b0.z, acc[3] * inv + b0.w,
                  acc[4] * inv + b4.x, acc[5] * inv + b4.y, acc[6] * inv + b4.z, acc[7] * inv + b4.w};
    f16x8 oh;
#pragma unroll
    for (int k = 0; k < 8; ++k) {
        float v = o[k];
        v = v > 0.f ? v : __expf(v) - 1.f;  // fused ELU
        oh[k] = (f16)v;
    }
    *(f16x8*)(h2s + ((size_t)sl * NNODES + n) * 32 + c0) = oh;
}

// Wave-per-node, single pass; lane = slot(4) x chpair(16), f16x2 gathers of gh
// (3.2 MB, L2-resident); alpha from L2-resident as2/ad2; u16 indices.
__global__ __launch_bounds__(256) void k_agg2(const int* __restrict__ rowst, const u16* __restrict__ sd16,
                                              const float* __restrict__ as2, const float* __restrict__ ad2,
                                              const f16* __restrict__ gh, const float* __restrict__ b2,
                                              float* __restrict__ out) {
    int w = threadIdx.x >> 6, lane = threadIdx.x & 63;
    int n = blockIdx.x * 4 + w;
    int s = rowst[n], e = rowst[n + 1];
    int slot = lane >> 4;
    int cp = lane & 15;  // channels 2cp, 2cp+1
    float adn = ad2[n];
    const f16* __restrict__ gp = gh + 2 * cp;
    float a0 = 0.f, a1 = 0.f, sum = 0.f;
    int j = s + slot;
    for (; j + 12 < e; j += 16) {
        int si[4];
#pragma unroll
        for (int u = 0; u < 4; ++u) si[u] = (int)sd16[j + 4 * u];
        float xv[4];
#pragma unroll
        for (int u = 0; u < 4; ++u) xv[u] = as2[si[u]];
        f16x2 vv[4];
#pragma unroll
        for (int u = 0; u < 4; ++u) vv[u] = *(const f16x2*)(gp + (size_t)si[u] * 32);
        float ee[4];
#pragma unroll
        for (int u = 0; u < 4; ++u) {
            float x = xv[u] + adn;
            x = fmaxf(x, 0.2f * x);
            ee[u] = __expf(x);
            sum += ee[u];
        }
#pragma unroll
        for (int u = 0; u < 4; ++u) a0 += ee[u] * (float)vv[u][0];
#pragma unroll
        for (int u = 0; u < 4; ++u) a1 += ee[u] * (float)vv[u][1];
    }
    for (; j + 4 < e; j += 8) {
        int s0 = (int)sd16[j];
        int s1 = (int)sd16[j + 4];
        float x0 = as2[s0] + adn, x1 = as2[s1] + adn;
        f16x2 v0 = *(const f16x2*)(gp + (size_t)s0 * 32);
        f16x2 v1 = *(const f16x2*)(gp + (size_t)s1 * 32);
        x0 = fmaxf(x0, 0.2f * x0);
        x1 = fmaxf(x1, 0.2f * x1);
        float e0 = __expf(x0), e1 = __expf(x1);
        sum += e0 + e1;
        a0 += e0 * (float)v0[0] + e1 * (float)v1[0];
        a1 += e0 * (float)v0[1] + e1 * (float)v1[1];
    }
    for (; j < e; j += 4) {
        int s0 = (int)sd16[j];
        float x0 = as2[s0] + adn;
        f16x2 v0 = *(const f16x2*)(gp + (size_t)s0 * 32);
        x0 = fmaxf(x0, 0.2f * x0);
        float e0 = __expf(x0);
        sum += e0;
        a0 += e0 * (float)v0[0];
        a1 += e0 * (float)v0[1];
    }
#pragma unroll
    for (int d = 16; d < 64; d <<= 1) {
        sum += __shfl_xor(sum, d);
        a0 += __shfl_xor(a0, d);
        a1 += __shfl_xor(a1, d);
    }
    if (slot == 0) {
        float inv = 1.f / (sum + 1e-16f);
        float2 o;
        o.x = a0 * inv + b2[2 * cp];
        o.y = a1 * inv + b2[2 * cp + 1];
        *(float2*)(out + (size_t)n * 32 + 2 * cp) = o;
    }
}

// ---------------- launch ----------------

extern "C" void kernel_launch(void* const* d_in, const int* in_sizes, int n_in,
                              void* d_out, int out_size, void* d_ws, size_t ws_size,
                              hipStream_t stream) {
    const float* x    = (const float*)d_in[0];
    const int*   ei   = (const int*)d_in[1];
    const float* W1   = (const float*)d_in[2];
    const float* As1  = (const float*)d_in[3];
    const float* Ad1  = (const float*)d_in[4];
    const float* b1   = (const float*)d_in[5];
    const float* W2   = (const float*)d_in[6];
    const float* As2  = (const float*)d_in[7];
    const float* Ad2  = (const float*)d_in[8];
    const float* b2   = (const float*)d_in[9];
    float* out = (float*)d_out;

    char* p = (char*)d_ws;
    auto alloc = [&](size_t bytes) -> char* {
        char* r = p;
        p += (bytes + 255) & ~(size_t)255;
        return r;
    };
    f16* h1s      = (f16*)alloc((size_t)NNODES * 256 * 2);   // [8][N][32] head-major
    f16* h2s      = (f16*)alloc((size_t)NNODES * 256 * 2);   // [8][N][32] head-major
    f16* W1f      = (f16*)alloc((size_t)128 * 256 * 2);
    f16* W2f      = (f16*)alloc((size_t)256 * 32 * 2);
    f16* gh       = (f16*)alloc((size_t)NNODES * 32 * 2);
    float* as1n   = (float*)alloc((size_t)NNODES * 8 * 4);   // [N][8] node-major
    float* ad1n   = (float*)alloc((size_t)NNODES * 8 * 4);
    float* asrc2  = (float*)alloc((size_t)NNODES * 4);
    float* adst2  = (float*)alloc((size_t)NNODES * 4);
    int* deg      = (int*)alloc((size_t)NNODES * 4);
    int* incl     = (int*)alloc((size_t)NNODES * 4);
    int* rowst    = (int*)alloc((size_t)(NNODES + 1) * 4);
    int* rank     = (int*)alloc((size_t)NEDGES * 4);
    unsigned* sdc = (unsigned*)alloc((size_t)NEDGES * 4);
    u16* sd16     = (u16*)alloc((size_t)NEDGES * 2);
    f16* eh16     = (f16*)alloc((size_t)8 * NEDGES * 2);     // [8][E] f16 exp planes
    int* partial  = (int*)alloc(256 * 4);

    const int EB = NEDGES / 256;           // 3125
    const int NCH = (NNODES + 255) / 256;  // 196

    hipMemsetAsync(deg, 0, (size_t)NNODES * 4, stream);
    k_deg_wfrag<<<EB + 160, 256, 0, stream>>>(ei, deg, rank, W1, W2, W1f, W2f);
    k_scanA<<<NCH, 256, 0, stream>>>(deg, incl, partial);
    k_scanC<<<NCH, 256, 0, stream>>>(deg, incl, partial, rowst);

    k_gemm1_sc<<<GB + EB, 256, 0, stream>>>(x, W1f, As1, Ad1, h1s, as1n, ad1n, ei, rowst, rank, sdc);
    k_exp<<<EB, 256, 0, stream>>>(sdc, as1n, ad1n, eh16, sd16);
    k_agg1<<<8 * GB, 256, 0, stream>>>(rowst, sd16, eh16, h1s, b1, h2s);

    k_gemm2<<<(NNODES + 63) / 64, 256, 0, stream>>>(h2s, W2f, As2, Ad2, gh, asrc2, adst2);
    k_agg2<<<NNODES / 4, 256, 0, stream>>>(rowst, sd16, asrc2, adst2, gh, b2, out);
}

// Round 11
// 247.129 us; speedup vs baseline: 1.1275x; 1.1275x over previous
//
#include <hip/hip_runtime.h>
#include <math.h>

#define NNODES 50000
#define NEDGES 800000
#define GB 782            // row-blocks = (NNODES+63)/64

typedef _Float16 f16;
typedef _Float16 f16x8 __attribute__((ext_vector_type(8)));
typedef _Float16 f16x4 __attribute__((ext_vector_type(4)));
typedef _Float16 f16x2 __attribute__((ext_vector_type(2)));
typedef float f32x4 __attribute__((ext_vector_type(4)));
typedef float f32x8 __attribute__((ext_vector_type(8)));
typedef unsigned short u16;

// ---------------- CSR build + weight pack ----------------

__global__ __launch_bounds__(256) void k_deg_wfrag(const int* __restrict__ ei, int* __restrict__ deg,
                                                   int* __restrict__ rank,
                                                   const float* __restrict__ W1, const float* __restrict__ W2,
                                                   f16* __restrict__ W1f, f16* __restrict__ W2f) {
    int bid = blockIdx.x;
    if (bid < NEDGES / 256) {
        int e = bid * 256 + threadIdx.x;
        rank[e] = atomicAdd(&deg[ei[NEDGES + e]], 1);
    } else {
        int id = (bid - NEDGES / 256) * 256 + threadIdx.x;
        if (id < 32768) {  // W1: 128 x 256
            int k = id >> 8, c = id & 255;
            int kc = k >> 5, quad = (k & 31) >> 3, j = k & 7;
            W1f[(((kc << 8) + c) * 4 + quad) * 8 + j] = (f16)W1[id];
        } else {           // W2: 256 x 32
            int i2 = id - 32768;
            int k = i2 >> 5, c = i2 & 31;
            int kc = k >> 5, quad = (k & 31) >> 3, j = k & 7;
            W2f[(((kc << 5) + c) * 4 + quad) * 8 + j] = (f16)W2[i2];
        }
    }
}

__global__ __launch_bounds__(256) void k_scanA(const int* __restrict__ deg, int* __restrict__ incl,
                                               int* __restrict__ partial) {
    int t = threadIdx.x;
    int i = blockIdx.x * 256 + t;
    int v = (i < NNODES) ? deg[i] : 0;
    int lane = t & 63, wid = t >> 6;
    int s = v;
#pragma unroll
    for (int d = 1; d < 64; d <<= 1) { int u = __shfl_up(s, d, 64); if (lane >= d) s += u; }
    __shared__ int wtot[4];
    if (lane == 63) wtot[wid] = s;
    __syncthreads();
    int off = 0;
    for (int w = 0; w < wid; ++w) off += wtot[w];
    s += off;
    if (i < NNODES) incl[i] = s;
    if (t == 255) partial[blockIdx.x] = s;
}

__global__ __launch_bounds__(256) void k_scanC(const int* __restrict__ deg, const int* __restrict__ incl,
                                               const int* __restrict__ partial, int* __restrict__ rowst) {
    int t = threadIdx.x, bid = blockIdx.x;
    int v = (t < bid) ? partial[t] : 0;  // bid <= 195 < 256
    int lane = t & 63, wid = t >> 6;
#pragma unroll
    for (int d = 1; d < 64; d <<= 1) v += __shfl_xor(v, d);
    __shared__ int ws[4];
    if (lane == 0) ws[wid] = v;
    __syncthreads();
    int choff = ws[0] + ws[1] + ws[2] + ws[3];
    int i = bid * 256 + t;
    if (i < NNODES) {
        int rs1 = incl[i] + choff;
        rowst[i + 1] = rs1;
        if (i == 0) rowst[0] = 0;
    }
}

// ---------------- gemm1 + atomic-free thin scatter (merged grid) ----------------
// Wave-per-64-col strip (R3); head-major h1s[head][node][32] (R4);
// node-major f32 alphas as1n/ad1n[N][8] for k_exp's 32B endpoint gathers (R7).

__global__ __launch_bounds__(256) void k_gemm1_sc(const float* __restrict__ X, const f16* __restrict__ W1f,
                                                  const float* __restrict__ Asrc, const float* __restrict__ Adst,
                                                  f16* __restrict__ h1s, float* __restrict__ as1n,
                                                  float* __restrict__ ad1n, const int* __restrict__ ei,
                                                  const int* __restrict__ rowst, const int* __restrict__ rank,
                                                  unsigned* __restrict__ sd32) {
    __shared__ f16 sA[64 * 136];
    int bid = blockIdx.x;
    int t = threadIdx.x;
    if (bid >= GB) {  // CSR scatter path (uniform per block)
        int e = (bid - GB) * 256 + t;
        if (e < NEDGES) {
            int s = ei[e], d = ei[NEDGES + e];
            int pos = rowst[d] + rank[e];
            sd32[pos] = ((unsigned)d << 16) | (unsigned)s;
        }
        return;
    }
    int bm = bid * 64;
    int lane = t & 63, w = t >> 6;
    int r = lane & 15, quad = lane >> 4;
    int cw = w * 64;  // this wave's column strip = heads {2w, 2w+1}
    f16x8 bf[4][4];
#pragma unroll
    for (int kc = 0; kc < 4; ++kc)
#pragma unroll
        for (int nt = 0; nt < 4; ++nt)
            bf[kc][nt] = *(const f16x8*)&W1f[(((kc << 8) + cw + nt * 16 + r) * 4 + quad) * 8];
#pragma unroll
    for (int i = 0; i < 8; ++i) {
        int idx = i * 256 + t;
        int row = idx >> 5, c4 = (idx & 31) << 2;
        int gr = bm + row;
        float4 v = make_float4(0.f, 0.f, 0.f, 0.f);
        if (gr < NNODES) v = *(const float4*)(X + (size_t)gr * 128 + c4);
        f16x4 h = {(f16)v.x, (f16)v.y, (f16)v.z, (f16)v.w};
        *(f16x4*)&sA[row * 136 + c4] = h;
    }
    __syncthreads();
    f32x4 acc[4][4];
#pragma unroll
    for (int rg = 0; rg < 4; ++rg)
#pragma unroll
        for (int nt = 0; nt < 4; ++nt) acc[rg][nt] = (f32x4){0.f, 0.f, 0.f, 0.f};
#pragma unroll
    for (int kc = 0; kc < 4; ++kc)
#pragma unroll
        for (int rg = 0; rg < 4; ++rg) {
            f16x8 a = *(f16x8*)&sA[(rg * 16 + r) * 136 + kc * 32 + quad * 8];
#pragma unroll
            for (int nt = 0; nt < 4; ++nt)
                acc[rg][nt] = __builtin_amdgcn_mfma_f32_16x16x32_f16(a, bf[kc][nt], acc[rg][nt], 0, 0, 0);
        }
#pragma unroll
    for (int rg = 0; rg < 4; ++rg)
#pragma unroll
        for (int nt = 0; nt < 4; ++nt)
#pragma unroll
            for (int i = 0; i < 4; ++i) {
                int gr = bm + rg * 16 + quad * 4 + i;
                if (gr < NNODES)
                    h1s[((size_t)(2 * w + (nt >> 1)) * NNODES + gr) * 32 + (nt & 1) * 16 + r] =
                        (f16)acc[rg][nt][i];
            }
    float asv[4], adv[4];
#pragma unroll
    for (int nt = 0; nt < 4; ++nt) {
        asv[nt] = Asrc[cw + nt * 16 + r];
        adv[nt] = Adst[cw + nt * 16 + r];
    }
#pragma unroll
    for (int rg = 0; rg < 4; ++rg)
#pragma unroll
        for (int i = 0; i < 4; ++i) {
            int gr = bm + rg * 16 + quad * 4 + i;
#pragma unroll
            for (int hh = 0; hh < 2; ++hh) {
                float ps = acc[rg][2 * hh][i] * asv[2 * hh] + acc[rg][2 * hh + 1][i] * asv[2 * hh + 1];
                float pd = acc[rg][2 * hh][i] * adv[2 * hh] + acc[rg][2 * hh + 1][i] * adv[2 * hh + 1];
#pragma unroll
                for (int off = 1; off < 16; off <<= 1) {
                    ps += __shfl_xor(ps, off);
                    pd += __shfl_xor(pd, off);
                }
                if (r == 0 && gr < NNODES) {
                    as1n[(size_t)gr * 8 + 2 * w + hh] = ps;   // node-major
                    ad1n[(size_t)gr * 8 + 2 * w + hh] = pd;
                }
            }
        }
}

// ---------------- edge-exp precompute ----------------
// Thread-per-edge. One 32B alpha gather per endpoint; leaky+exp for all 8
// heads; writes f16 exp planes eh16[8][E] (12.8 MB) + u16 src indices
// (1.6 MB) — half of R9's stream footprint, the thrash lever that R9's 63us
// tolerated. Removes the 6.4M-line alpha gather from agg1's hot loop.
__global__ __launch_bounds__(256) void k_exp(const unsigned* __restrict__ sd32, const float* __restrict__ as1n,
                                             const float* __restrict__ ad1n, f16* __restrict__ eh16,
                                             u16* __restrict__ sd16) {
    int j = blockIdx.x * 256 + threadIdx.x;
    if (j >= NEDGES) return;
    unsigned q = sd32[j];
    int d = (int)(q >> 16);
    int s = (int)(q & 0xffffu);
    sd16[j] = (u16)s;
    float4 a0 = *(const float4*)(as1n + (size_t)s * 8);
    float4 a1 = *(const float4*)(as1n + (size_t)s * 8 + 4);
    float4 d0 = *(const float4*)(ad1n + (size_t)d * 8);
    float4 d1 = *(const float4*)(ad1n + (size_t)d * 8 + 4);
    float av[8] = {a0.x, a0.y, a0.z, a0.w, a1.x, a1.y, a1.z, a1.w};
    float dv[8] = {d0.x, d0.y, d0.z, d0.w, d1.x, d1.y, d1.z, d1.w};
#pragma unroll
    for (int h = 0; h < 8; ++h) {
        float x = av[h] + dv[h];
        x = fmaxf(x, 0.2f * x);
        eh16[(size_t)h * NEDGES + j] = (f16)__expf(x);
    }
}

// gh[N,32](f16) = h2 @ W2; h2 is head-major h2s[head][node][32] (kc == head).
__global__ __launch_bounds__(256) void k_gemm2(const f16* __restrict__ h2s, const f16* __restrict__ W2f,
                                               const float* __restrict__ Asrc, const float* __restrict__ Adst,
                                               f16* __restrict__ gh, float* __restrict__ as2,
                                               float* __restrict__ ad2) {
    int t = threadIdx.x;
    int bm = blockIdx.x * 64;
    int lane = t & 63, w = t >> 6;
    int r = lane & 15, quad = lane >> 4;
    int r0 = w * 16;
    int gra = bm + r0 + r;
    int grac = gra < NNODES ? gra : 0;
    f32x4 acc[2];
    acc[0] = (f32x4){0.f, 0.f, 0.f, 0.f};
    acc[1] = (f32x4){0.f, 0.f, 0.f, 0.f};
#pragma unroll
    for (int kc = 0; kc < 8; ++kc) {
        f16x8 a = *(const f16x8*)(h2s + ((size_t)kc * NNODES + grac) * 32 + quad * 8);
#pragma unroll
        for (int nt = 0; nt < 2; ++nt) {
            f16x8 b = *(const f16x8*)&W2f[(((kc << 5) + nt * 16 + r) * 4 + quad) * 8];
            acc[nt] = __builtin_amdgcn_mfma_f32_16x16x32_f16(a, b, acc[nt], 0, 0, 0);
        }
    }
#pragma unroll
    for (int nt = 0; nt < 2; ++nt)
#pragma unroll
        for (int i = 0; i < 4; ++i) {
            int gr = bm + r0 + quad * 4 + i;
            if (gr < NNODES) gh[(size_t)gr * 32 + nt * 16 + r] = (f16)acc[nt][i];
        }
    float as0 = Asrc[r], as16 = Asrc[16 + r];
    float ad0 = Adst[r], ad16 = Adst[16 + r];
#pragma unroll
    for (int i = 0; i < 4; ++i) {
        int gr = bm + r0 + quad * 4 + i;
        float ps = acc[0][i] * as0 + acc[1][i] * as16;
        float pd = acc[0][i] * ad0 + acc[1][i] * ad16;
#pragma unroll
        for (int off = 1; off < 16; off <<= 1) {
            ps += __shfl_xor(ps, off);
            pd += __shfl_xor(pd, off);
        }
        if (r == 0 && gr < NNODES) { as2[gr] = ps; ad2[gr] = pd; }
    }
}

// ---------------- fused softmax + aggregate ----------------
// R11: R9's structure (best measured agg1, 63us) with halved streams and
// NORMAL loads. R10 post-mortem: nontemporal scalar 2B loads collapsed issue
// efficiency (VALUBusy 39->31, dur 63->81) — nt was the regression, not the
// stream shrink (FETCH 132->60 confirmed the shrink worked). Streams: u16
// indices + f16 exp planes (14.4 MB total vs R9's 28.8). h1s slice (3.2 MB)
// stays L2-resident via the R4 slice/XCD partition. Forced-live channel-major
// math (R6). Wave: 16 groups x 4 lanes; group owns one node; no reduce.
__global__ __launch_bounds__(256) void k_agg1(const int* __restrict__ rowst, const u16* __restrict__ sd16,
                                              const f16* __restrict__ eh16, const f16* __restrict__ h1s,
                                              const float* __restrict__ b1, f16* __restrict__ h2s) {
    int bid = blockIdx.x;
    int sl = bid & 7;
    int ng = bid >> 3;
    int t = threadIdx.x;
    int w = t >> 6, lane = t & 63;
    int g = lane >> 2, cs = lane & 3;
    int c0 = cs << 3;
    int n = ng * 64 + w * 16 + g;
    if (n >= NNODES) return;
    int s = rowst[n], e = rowst[n + 1];
    const f16* __restrict__ hp = h1s + (size_t)sl * NNODES * 32 + c0;
    const f16* __restrict__ ep = eh16 + (size_t)sl * NEDGES;
    f32x8 acc = (f32x8){0.f, 0.f, 0.f, 0.f, 0.f, 0.f, 0.f, 0.f};
    float sum = 0.f;
    int j = s;
    for (; j + 7 < e; j += 8) {
        int si[8];
#pragma unroll
        for (int u = 0; u < 8; ++u) si[u] = (int)sd16[j + u];
        float ee[8];
#pragma unroll
        for (int u = 0; u < 8; ++u) ee[u] = (float)ep[j + u];
        f16x8 vv[8];
#pragma unroll
        for (int u = 0; u < 8; ++u) vv[u] = *(const f16x8*)(hp + (size_t)si[u] * 32);
#pragma unroll
        for (int u = 0; u < 8; ++u) sum += ee[u];
        // channel-major: all 8 gathers live across the math block (forced MLP)
#pragma unroll
        for (int k = 0; k < 8; ++k) {
            float a = acc[k];
#pragma unroll
            for (int u = 0; u < 8; ++u) a += ee[u] * (float)vv[u][k];
            acc[k] = a;
        }
    }
    for (; j + 3 < e; j += 4) {
        int si[4];
#pragma unroll
        for (int u = 0; u < 4; ++u) si[u] = (int)sd16[j + u];
        float ee[4];
#pragma unroll
        for (int u = 0; u < 4; ++u) ee[u] = (float)ep[j + u];
        f16x8 vv[4];
#pragma unroll
        for (int u = 0; u < 4; ++u) vv[u] = *(const f16x8*)(hp + (size_t)si[u] * 32);
#pragma unroll
        for (int u = 0; u < 4; ++u) sum += ee[u];
#pragma unroll
        for (int k = 0; k < 8; ++k) {
            float a = acc[k];
#pragma unroll
            for (int u = 0; u < 4; ++u) a += ee[u] * (float)vv[u][k];
            acc[k] = a;
        }
    }
    for (; j < e; ++j) {
        int s0 = (int)sd16[j];
        float e0 = (float)ep[j];
        f16x8 v0 = *(const f16x8*)(hp + (size_t)s0 * 32);
        sum += e0;
#pragma unroll
        for (int k = 0; k < 8; ++k) acc[k] += e0 * (float)v0[k];
    }
    float inv = 1.f / (sum + 1e-16f);
    float4 b0 = *(const float4*)(b1 + sl * 32 + c0);
    float4 b4 = *(const float4*)(b1 + sl * 32 + c0 + 4);
    float o[8] = {acc[0] * inv + b0.x, acc[1] * inv + b0.y, acc[2] * inv + b0.z, acc[3] * inv + b0.w,
                  acc[4] * inv + b4.x, acc[5] * inv + b4.y, acc[6] * inv + b4.z, acc[7] * inv + b4.w};
    f16x8 oh;
#pragma unroll
    for (int k = 0; k < 8; ++k) {
        float v = o[k];
        v = v > 0.f ? v : __expf(v) - 1.f;  // fused ELU
        oh[k] = (f16)v;
    }
    *(f16x8*)(h2s + ((size_t)sl * NNODES + n) * 32 + c0) = oh;
}

// Wave-per-node, single pass; lane = slot(4) x chpair(16), f16x2 gathers of gh
// (3.2 MB, L2-resident); alpha from L2-resident as2/ad2; u16 indices.
__global__ __launch_bounds__(256) void k_agg2(const int* __restrict__ rowst, const u16* __restrict__ sd16,
                                              const float* __restrict__ as2, const float* __restrict__ ad2,
                                              const f16* __restrict__ gh, const float* __restrict__ b2,
                                              float* __restrict__ out) {
    int w = threadIdx.x >> 6, lane = threadIdx.x & 63;
    int n = blockIdx.x * 4 + w;
    int s = rowst[n], e = rowst[n + 1];
    int slot = lane >> 4;
    int cp = lane & 15;  // channels 2cp, 2cp+1
    float adn = ad2[n];
    const f16* __restrict__ gp = gh + 2 * cp;
    float a0 = 0.f, a1 = 0.f, sum = 0.f;
    int j = s + slot;
    for (; j + 12 < e; j += 16) {
        int si[4];
#pragma unroll
        for (int u = 0; u < 4; ++u) si[u] = (int)sd16[j + 4 * u];
        float xv[4];
#pragma unroll
        for (int u = 0; u < 4; ++u) xv[u] = as2[si[u]];
        f16x2 vv[4];
#pragma unroll
        for (int u = 0; u < 4; ++u) vv[u] = *(const f16x2*)(gp + (size_t)si[u] * 32);
        float ee[4];
#pragma unroll
        for (int u = 0; u < 4; ++u) {
            float x = xv[u] + adn;
            x = fmaxf(x, 0.2f * x);
            ee[u] = __expf(x);
            sum += ee[u];
        }
#pragma unroll
        for (int u = 0; u < 4; ++u) a0 += ee[u] * (float)vv[u][0];
#pragma unroll
        for (int u = 0; u < 4; ++u) a1 += ee[u] * (float)vv[u][1];
    }
    for (; j + 4 < e; j += 8) {
        int s0 = (int)sd16[j];
        int s1 = (int)sd16[j + 4];
        float x0 = as2[s0] + adn, x1 = as2[s1] + adn;
        f16x2 v0 = *(const f16x2*)(gp + (size_t)s0 * 32);
        f16x2 v1 = *(const f16x2*)(gp + (size_t)s1 * 32);
        x0 = fmaxf(x0, 0.2f * x0);
        x1 = fmaxf(x1, 0.2f * x1);
        float e0 = __expf(x0), e1 = __expf(x1);
        sum += e0 + e1;
        a0 += e0 * (float)v0[0] + e1 * (float)v1[0];
        a1 += e0 * (float)v0[1] + e1 * (float)v1[1];
    }
    for (; j < e; j += 4) {
        int s0 = (int)sd16[j];
        float x0 = as2[s0] + adn;
        f16x2 v0 = *(const f16x2*)(gp + (size_t)s0 * 32);
        x0 = fmaxf(x0, 0.2f * x0);
        float e0 = __expf(x0);
        sum += e0;
        a0 += e0 * (float)v0[0];
        a1 += e0 * (float)v0[1];
    }
#pragma unroll
    for (int d = 16; d < 64; d <<= 1) {
        sum += __shfl_xor(sum, d);
        a0 += __shfl_xor(a0, d);
        a1 += __shfl_xor(a1, d);
    }
    if (slot == 0) {
        float inv = 1.f / (sum + 1e-16f);
        float2 o;
        o.x = a0 * inv + b2[2 * cp];
        o.y = a1 * inv + b2[2 * cp + 1];
        *(float2*)(out + (size_t)n * 32 + 2 * cp) = o;
    }
}

// ---------------- launch ----------------

extern "C" void kernel_launch(void* const* d_in, const int* in_sizes, int n_in,
                              void* d_out, int out_size, void* d_ws, size_t ws_size,
                              hipStream_t stream) {
    const float* x    = (const float*)d_in[0];
    const int*   ei   = (const int*)d_in[1];
    const float* W1   = (const float*)d_in[2];
    const float* As1  = (const float*)d_in[3];
    const float* Ad1  = (const float*)d_in[4];
    const float* b1   = (const float*)d_in[5];
    const float* W2   = (const float*)d_in[6];
    const float* As2  = (const float*)d_in[7];
    const float* Ad2  = (const float*)d_in[8];
    const float* b2   = (const float*)d_in[9];
    float* out = (float*)d_out;

    char* p = (char*)d_ws;
    auto alloc = [&](size_t bytes) -> char* {
        char* r = p;
        p += (bytes + 255) & ~(size_t)255;
        return r;
    };
    f16* h1s      = (f16*)alloc((size_t)NNODES * 256 * 2);   // [8][N][32] head-major
    f16* h2s      = (f16*)alloc((size_t)NNODES * 256 * 2);   // [8][N][32] head-major
    f16* W1f      = (f16*)alloc((size_t)128 * 256 * 2);
    f16* W2f      = (f16*)alloc((size_t)256 * 32 * 2);
    f16* gh       = (f16*)alloc((size_t)NNODES * 32 * 2);
    float* as1n   = (float*)alloc((size_t)NNODES * 8 * 4);   // [N][8] node-major
    float* ad1n   = (float*)alloc((size_t)NNODES * 8 * 4);
    float* asrc2  = (float*)alloc((size_t)NNODES * 4);
    float* adst2  = (float*)alloc((size_t)NNODES * 4);
    int* deg      = (int*)alloc((size_t)NNODES * 4);
    int* incl     = (int*)alloc((size_t)NNODES * 4);
    int* rowst    = (int*)alloc((size_t)(NNODES + 1) * 4);
    int* rank     = (int*)alloc((size_t)NEDGES * 4);
    unsigned* sdc = (unsigned*)alloc((size_t)NEDGES * 4);
    u16* sd16     = (u16*)alloc((size_t)NEDGES * 2);
    f16* eh16     = (f16*)alloc((size_t)8 * NEDGES * 2);     // [8][E] f16 exp planes
    int* partial  = (int*)alloc(256 * 4);

    const int EB = NEDGES / 256;           // 3125
    const int NCH = (NNODES + 255) / 256;  // 196

    hipMemsetAsync(deg, 0, (size_t)NNODES * 4, stream);
    k_deg_wfrag<<<EB + 160, 256, 0, stream>>>(ei, deg, rank, W1, W2, W1f, W2f);
    k_scanA<<<NCH, 256, 0, stream>>>(deg, incl, partial);
    k_scanC<<<NCH, 256, 0, stream>>>(deg, incl, partial, rowst);

    k_gemm1_sc<<<GB + EB, 256, 0, stream>>>(x, W1f, As1, Ad1, h1s, as1n, ad1n, ei, rowst, rank, sdc);
    k_exp<<<EB, 256, 0, stream>>>(sdc, as1n, ad1n, eh16, sd16);
    k_agg1<<<8 * GB, 256, 0, stream>>>(rowst, sd16, eh16, h1s, b1, h2s);

    k_gemm2<<<(NNODES + 63) / 64, 256, 0, stream>>>(h2s, W2f, As2, Ad2, gh, asrc2, adst2);
    k_agg2<<<NNODES / 4, 256, 0, stream>>>(rowst, sd16, asrc2, adst2, gh, b2, out);
}